// Round 2
// baseline (100236.975 us; speedup 1.0000x reference)
//
#include <hip/hip_runtime.h>
#include <hip/hip_bf16.h>
#include <cstdint>
#include <cstddef>

#define T_STEPS 32768
#define DD 64
#define HH 128
#define GG 512   // 4*H

// d_out layout (float32, concatenated flat):
//   step (T,11) @0, experience (T,2) @360448, rsd (T,1) @425984, s (T,1) @458752
#define OFF_EXP 360448
#define OFF_RSD 425984
#define OFF_S   458752

typedef __attribute__((ext_vector_type(8))) _Float16 half8;
typedef __attribute__((ext_vector_type(4))) float f32x4;

__device__ __forceinline__ float sigm_f(float x) {
    return 1.0f / (1.0f + __expf(-x));
}
__device__ __forceinline__ float tanh_f(float x) {
    // stable both directions
    return 1.0f - 2.0f / (__expf(2.0f * x) + 1.0f);
}

// ---------------------------------------------------------------------------
// Kernel 1: P[r][j] = dot(X[t0+r,:], W_ih[j,:]) + b_ih[j] + b_hh[j]
// ---------------------------------------------------------------------------
__global__ __launch_bounds__(512, 2) void pregate_kernel(
    const float* __restrict__ X, const float* __restrict__ W_ih,
    const float* __restrict__ b_ih, const float* __restrict__ b_hh,
    float* __restrict__ P, int t0, int nrows)
{
    __shared__ __align__(16) float xs[DD];
    const int j = threadIdx.x;

    float w[DD];
    const float4* wv = reinterpret_cast<const float4*>(W_ih + (size_t)j * DD);
#pragma unroll
    for (int k = 0; k < DD / 4; ++k) {
        float4 v = wv[k];
        w[4*k+0] = v.x; w[4*k+1] = v.y; w[4*k+2] = v.z; w[4*k+3] = v.w;
    }
    const float bias = b_ih[j] + b_hh[j];

    const int rpb = (nrows + gridDim.x - 1) / gridDim.x;
    const int r0  = blockIdx.x * rpb;
    const int r1  = (r0 + rpb < nrows) ? (r0 + rpb) : nrows;

    for (int r = r0; r < r1; ++r) {
        const int t = t0 + r;
        if (j < DD) xs[j] = X[(size_t)t * DD + j];
        __syncthreads();
        float acc = bias;
        const float4* xv = reinterpret_cast<const float4*>(xs);
#pragma unroll
        for (int k = 0; k < DD / 4; ++k) {
            float4 v = xv[k];
            acc += v.x*w[4*k+0] + v.y*w[4*k+1] + v.z*w[4*k+2] + v.w*w[4*k+3];
        }
        P[(size_t)r * GG + j] = acc;
        __syncthreads();
    }
}

// ---------------------------------------------------------------------------
// Heads: 15 outputs = dot(h, WH[o,:]) + bh[o]; 8 lanes per output, jj in [0,120)
// ---------------------------------------------------------------------------
__device__ __forceinline__ void do_heads(int jj, int gt,
                                         const float* __restrict__ h,
                                         const float* __restrict__ wh,
                                         const float* __restrict__ bh,
                                         float* __restrict__ out)
{
    if (jj >= 120) return;
    const int oi = jj >> 3;   // 0..14
    const int l8 = jj & 7;
    const float* hp = h + l8 * 16;
    const float* wp = wh + oi * HH + l8 * 16;
    float s = 0.0f;
#pragma unroll
    for (int i = 0; i < 16; ++i) s += hp[i] * wp[i];
    s += __shfl_down(s, 4);
    s += __shfl_down(s, 2);
    s += __shfl_down(s, 1);
    if (l8 == 0) {
        s += bh[oi];
        if (oi < 11)       out[(size_t)gt * 11 + oi] = s;
        else if (oi < 13)  out[OFF_EXP + (size_t)gt * 2 + (oi - 11)] = s;
        else if (oi == 13) out[OFF_RSD + gt] = s;
        else               out[OFF_S   + gt] = s;
    }
}

// ---------------------------------------------------------------------------
// Kernel 2: sequential LSTM, 1 block x 512 threads (8 waves).
// Wave w owns gates [64w, 64w+64). Recurrent matvec via f16 MFMA:
//   A = W_hh tiles (f16, registers, loaded once), B = h replicated 16 cols.
// Lane layout (16x16x32): A row = lane&15, k = 8*(lane>>4)+e;
//   D col = lane&15, row = (lane>>4)*4 + reg  [HW-verified mapping].
// ---------------------------------------------------------------------------
__global__ __launch_bounds__(512, 2) void lstm_seq_kernel(
    const float* __restrict__ P, const float* __restrict__ W_hh,
    const float* __restrict__ W1, const float* __restrict__ b1,
    const float* __restrict__ W2, const float* __restrict__ b2,
    const float* __restrict__ W3, const float* __restrict__ b3,
    const float* __restrict__ W4, const float* __restrict__ b4,
    float* __restrict__ out, float* __restrict__ state,
    int t0, int C)
{
    __shared__ __align__(16) _Float16 hh[HH];       // h as f16 (MFMA B source)
    __shared__ __align__(16) float hbuf[2][HH];     // h fp32, double-buffered
    __shared__ __align__(16) float gate_lds[GG];    // activated gates
    __shared__ __align__(16) float wh[15 * HH];
    __shared__ float bh[15];

    const int j = threadIdx.x;
    const int w = j >> 6;          // wave 0..7
    const int l = j & 63;
    const int row16 = l & 15;
    const int kgrp  = l >> 4;      // 0..3
    const bool writer = (row16 == 0);
    const int wtype = w >> 1;      // 0=i(sig) 1=f(sig) 2=g(tanh) 3=o(sig)

    // ---- A fragments: W_hh -> f16 registers (4 M-tiles x 4 K-tiles x 8 f16)
    half8 afrag[4][4];
#pragma unroll
    for (int mt = 0; mt < 4; ++mt) {
        const int g = 64 * w + 16 * mt + row16;
        const float* wr = W_hh + (size_t)g * HH;
#pragma unroll
        for (int kt = 0; kt < 4; ++kt) {
            const float* wp = wr + 32 * kt + 8 * kgrp;
            float4 w0 = *reinterpret_cast<const float4*>(wp);
            float4 w1 = *reinterpret_cast<const float4*>(wp + 4);
            half8 a;
            a[0] = (_Float16)w0.x; a[1] = (_Float16)w0.y;
            a[2] = (_Float16)w0.z; a[3] = (_Float16)w0.w;
            a[4] = (_Float16)w1.x; a[5] = (_Float16)w1.y;
            a[6] = (_Float16)w1.z; a[7] = (_Float16)w1.w;
            afrag[mt][kt] = a;
        }
    }

    // ---- head weights -> LDS (15 x 128)
    for (int i = j; i < 15 * HH; i += GG) {
        const int r = i >> 7;
        const int cidx = i & (HH - 1);
        float v;
        if (r < 11)       v = W1[r * HH + cidx];
        else if (r < 13)  v = W2[(r - 11) * HH + cidx];
        else if (r == 13) v = W3[cidx];
        else              v = W4[cidx];
        wh[i] = v;
    }
    if (j < 15) {
        bh[j] = (j < 11) ? b1[j] : (j < 13) ? b2[j - 11] : (j == 13) ? b3[0] : b4[0];
    }

    float c = 0.0f;
    if (j < HH) {
        float h0 = 0.0f;
        if (t0 != 0) { h0 = state[j]; c = state[HH + j]; }
        hh[j] = (_Float16)h0;
    }
    __syncthreads();

    // pregate prefetch (writer lanes only): gate base for this lane's rows
    const int gi0 = 64 * w + 4 * kgrp;   // + 16*mt, rows are 4 consecutive gates
    f32x4 pc[4], pn[4] = {};
    if (writer) {
#pragma unroll
        for (int mt = 0; mt < 4; ++mt)
            pc[mt] = *reinterpret_cast<const f32x4*>(P + gi0 + 16 * mt);
    }

#pragma unroll 1
    for (int r = 0; r < C; ++r) {
        // issue next-step P loads early (hide L2 latency under MFMA)
        if (writer && (r + 1) < C) {
#pragma unroll
            for (int mt = 0; mt < 4; ++mt)
                pn[mt] = *reinterpret_cast<const f32x4*>(
                    P + (size_t)(r + 1) * GG + gi0 + 16 * mt);
        }

        // B fragments: 8 f16 of h per lane-group (broadcast b128 reads)
        half8 bfrag[4];
#pragma unroll
        for (int kt = 0; kt < 4; ++kt)
            bfrag[kt] = *reinterpret_cast<const half8*>(hh + 32 * kt + 8 * kgrp);

        // MFMA: acc[mt] = W_tile . h_rep
        f32x4 acc[4];
#pragma unroll
        for (int mt = 0; mt < 4; ++mt) {
            f32x4 a = {0.f, 0.f, 0.f, 0.f};
#pragma unroll
            for (int kt = 0; kt < 4; ++kt)
                a = __builtin_amdgcn_mfma_f32_16x16x32_f16(afrag[mt][kt], bfrag[kt], a, 0, 0, 0);
            acc[mt] = a;
        }

        // writer lanes (col 0): add pregate, activate, store 4 gates as b128
        if (writer) {
#pragma unroll
            for (int mt = 0; mt < 4; ++mt) {
                f32x4 v = acc[mt] + pc[mt];
                f32x4 g;
                if (wtype == 2) {
                    g[0] = tanh_f(v[0]); g[1] = tanh_f(v[1]);
                    g[2] = tanh_f(v[2]); g[3] = tanh_f(v[3]);
                } else {
                    g[0] = sigm_f(v[0]); g[1] = sigm_f(v[1]);
                    g[2] = sigm_f(v[2]); g[3] = sigm_f(v[3]);
                }
                *reinterpret_cast<f32x4*>(&gate_lds[gi0 + 16 * mt]) = g;
                pc[mt] = pn[mt];
            }
        }
        __syncthreads();

        // cell update (waves 0-1) || heads for previous row (waves 2-3)
        if (j < HH) {
            const float ig = gate_lds[j];
            const float fg = gate_lds[HH + j];
            const float gg = gate_lds[2 * HH + j];
            const float og = gate_lds[3 * HH + j];
            c = fg * c + ig * gg;
            const float h = og * tanh_f(c);
            hbuf[r & 1][j] = h;
            hh[j] = (_Float16)h;
        } else if (j < 256 && r > 0) {
            do_heads(j - 128, t0 + r - 1, hbuf[(r - 1) & 1], wh, bh, out);
        }
        __syncthreads();
    }

    // heads for this chunk's last row; persist state for next chunk
    if (j >= 128 && j < 256) do_heads(j - 128, t0 + C - 1, hbuf[(C - 1) & 1], wh, bh, out);
    if (j < HH) {
        state[j]      = hbuf[(C - 1) & 1][j];
        state[HH + j] = c;
    }
}

// ---------------------------------------------------------------------------
extern "C" void kernel_launch(void* const* d_in, const int* in_sizes, int n_in,
                              void* d_out, int out_size, void* d_ws, size_t ws_size,
                              hipStream_t stream)
{
    const float* X    = (const float*)d_in[0];
    const float* W_ih = (const float*)d_in[1];
    const float* W_hh = (const float*)d_in[2];
    const float* b_ih = (const float*)d_in[3];
    const float* b_hh = (const float*)d_in[4];
    const float* W1   = (const float*)d_in[5];
    const float* b1   = (const float*)d_in[6];
    const float* W2   = (const float*)d_in[7];
    const float* b2   = (const float*)d_in[8];
    const float* W3   = (const float*)d_in[9];
    const float* b3   = (const float*)d_in[10];
    const float* W4   = (const float*)d_in[11];
    const float* b4   = (const float*)d_in[12];

    float* out   = (float*)d_out;
    float* state = (float*)d_ws;          // 256 floats: h then c
    float* P     = state + 256;

    size_t avail_rows = (ws_size > 1024) ? (ws_size - 1024) / (GG * sizeof(float)) : 0;
    int C = (avail_rows >= (size_t)T_STEPS) ? T_STEPS : (int)avail_rows;
    if (C < 1) C = 1;

    for (int t0 = 0; t0 < T_STEPS; t0 += C) {
        const int Cc = (C < T_STEPS - t0) ? C : (T_STEPS - t0);
        const int nb = (Cc < 512) ? Cc : 512;
        pregate_kernel<<<nb, 512, 0, stream>>>(X, W_ih, b_ih, b_hh, P, t0, Cc);
        lstm_seq_kernel<<<1, 512, 0, stream>>>(P, W_hh, W1, b1, W2, b2, W3, b3, W4, b4,
                                               out, state, t0, Cc);
    }
}

// Round 3
// 17223.228 us; speedup vs baseline: 5.8199x; 5.8199x over previous
//
#include <hip/hip_runtime.h>
#include <hip/hip_bf16.h>
#include <cstdint>
#include <cstddef>

#define T_STEPS 32768
#define DD 64
#define HH 128
#define GG 512   // 4*H

// d_out layout (float32, concatenated flat):
//   step (T,11) @0, experience (T,2) @360448, rsd (T,1) @425984, s (T,1) @458752
#define OFF_EXP 360448
#define OFF_RSD 425984
#define OFF_S   458752

typedef __attribute__((ext_vector_type(2))) _Float16 half2v;

__device__ __forceinline__ int   f2i(float x) { union { float f; int i; } u; u.f = x; return u.i; }
__device__ __forceinline__ float i2f(int x)   { union { int i; float f; } u; u.i = x; return u.f; }

// quad_perm cross-lane move via DPP (pure VALU, no LDS pipe)
template<int CTRL>
__device__ __forceinline__ float qdpp(float v) {
    return i2f(__builtin_amdgcn_mov_dpp(f2i(v), CTRL, 0xf, 0xf, true));
}
// ctrl = p0 | p1<<2 | p2<<4 | p3<<6
#define QP_XOR1 0xB1  // (1,0,3,2)
#define QP_XOR2 0x4E  // (2,3,0,1)
#define QP_BC0  0x00
#define QP_BC1  0x55
#define QP_BC2  0xAA
#define QP_BC3  0xFF

__device__ __forceinline__ float dot2(unsigned w, unsigned h, float acc) {
    union { unsigned u; half2v h; } a, b;
    a.u = w; b.u = h;
    return __builtin_amdgcn_fdot2(a.h, b.h, acc, false);
}
__device__ __forceinline__ unsigned packh2(float x, float y) {
    union { half2v h; unsigned u; } c;
    c.h[0] = (_Float16)x; c.h[1] = (_Float16)y;
    return c.u;
}

// ---------------------------------------------------------------------------
// Kernel 1: pregate, PERMUTED layout: P[r][j] where thread j <-> gate (j&3)
// of cell (j>>2), i.e. original gate row grow = (j&3)*128 + (j>>2).
// ---------------------------------------------------------------------------
__global__ __launch_bounds__(512, 2) void pregate_kernel(
    const float* __restrict__ X, const float* __restrict__ W_ih,
    const float* __restrict__ b_ih, const float* __restrict__ b_hh,
    float* __restrict__ P, int t0, int nrows)
{
    __shared__ __align__(16) float xs[DD];
    const int j = threadIdx.x;
    const int grow = (j & 3) * HH + (j >> 2);

    float w[DD];
    const float4* wv = reinterpret_cast<const float4*>(W_ih + (size_t)grow * DD);
#pragma unroll
    for (int k = 0; k < DD / 4; ++k) {
        float4 v = wv[k];
        w[4*k+0] = v.x; w[4*k+1] = v.y; w[4*k+2] = v.z; w[4*k+3] = v.w;
    }
    const float bias = b_ih[grow] + b_hh[grow];

    const int rpb = (nrows + gridDim.x - 1) / gridDim.x;
    const int r0  = blockIdx.x * rpb;
    const int r1  = (r0 + rpb < nrows) ? (r0 + rpb) : nrows;

    for (int r = r0; r < r1; ++r) {
        const int t = t0 + r;
        if (j < DD) xs[j] = X[(size_t)t * DD + j];
        __syncthreads();
        float acc = bias;
        const float4* xv = reinterpret_cast<const float4*>(xs);
#pragma unroll
        for (int k = 0; k < DD / 4; ++k) {
            float4 v = xv[k];
            acc += v.x*w[4*k+0] + v.y*w[4*k+1] + v.z*w[4*k+2] + v.w*w[4*k+3];
        }
        P[(size_t)r * GG + j] = acc;
        __syncthreads();
    }
}

// ---------------------------------------------------------------------------
// Kernel 2: sequential LSTM, 1 block x 512 threads, ONE raw barrier per step.
// Lane quad owns cell (j>>2); lane q=(j&3) holds quarter-q of W_hh rows for
// all 4 gates of its cell as packed f16x2 in 64 pinned VGPRs.
// Per step: 4 broadcast ds_read_b128 of h (f16), 64 v_dot2_f32_f16,
// DPP quad butterfly, 1 activation/lane, DPP gate broadcast, replicated c.
// h streamed to hist[] for the parallel heads kernel.
// ---------------------------------------------------------------------------
__global__ __launch_bounds__(512, 2) void lstm_seq_kernel(
    const float* __restrict__ P, const float* __restrict__ W_hh,
    float* __restrict__ hist, float* __restrict__ state,
    int t0, int C)
{
    __shared__ __align__(16) _Float16 hh2[2][HH];

    const int j    = threadIdx.x;
    const int cell = j >> 2;
    const int q    = j & 3;

    // W_hh quarters -> packed f16x2 registers (64 VGPRs), pinned.
    unsigned w2[4][16];
#pragma unroll
    for (int g = 0; g < 4; ++g) {
        const float* wr = W_hh + (size_t)(g * HH + cell) * HH + 32 * q;
#pragma unroll
        for (int k = 0; k < 16; ++k)
            w2[g][k] = packh2(wr[2*k], wr[2*k+1]);
    }
#pragma unroll
    for (int g = 0; g < 4; ++g)
#pragma unroll
        for (int k = 0; k < 16; ++k)
            asm volatile("" : "+v"(w2[g][k]));   // forbid remat/demotion

    float c = 0.0f;
    if (t0 != 0) c = state[HH + cell];
    if (j < HH) hh2[0][j] = (_Float16)((t0 != 0) ? state[j] : 0.0f);
    __syncthreads();

    // pregate scalar stream, 2-deep prefetch (P[r*512 + j] is gate q of cell)
    float pcq = P[j];
    float pn1 = (C > 1) ? P[GG + j] : 0.0f;
    float hn  = 0.0f;

#pragma unroll 2
    for (int r = 0; r < C; ++r) {
        float pn2 = (r + 2 < C) ? P[(size_t)(r + 2) * GG + j] : 0.0f;

        const int cur = r & 1;
        const int nxt = cur ^ 1;

        // h quarter: 32 f16 = 4 x b128 (16-lane broadcast, conflict-free)
        unsigned hreg[16];
        const uint4* hp = reinterpret_cast<const uint4*>(&hh2[cur][32 * q]);
#pragma unroll
        for (int k = 0; k < 4; ++k) {
            uint4 v = hp[k];
            hreg[4*k+0] = v.x; hreg[4*k+1] = v.y;
            hreg[4*k+2] = v.z; hreg[4*k+3] = v.w;
        }

        // partial dots for all 4 gates over this lane's quarter
        float p0 = 0.f, p1 = 0.f, p2 = 0.f, p3 = 0.f;
#pragma unroll
        for (int k = 0; k < 16; ++k) {
            const unsigned hx = hreg[k];
            p0 = dot2(w2[0][k], hx, p0);
            p1 = dot2(w2[1][k], hx, p1);
            p2 = dot2(w2[2][k], hx, p2);
            p3 = dot2(w2[3][k], hx, p3);
        }
        // quad butterfly: all lanes end with full dots (bit-identical)
        p0 += qdpp<QP_XOR1>(p0); p1 += qdpp<QP_XOR1>(p1);
        p2 += qdpp<QP_XOR1>(p2); p3 += qdpp<QP_XOR1>(p3);
        p0 += qdpp<QP_XOR2>(p0); p1 += qdpp<QP_XOR2>(p1);
        p2 += qdpp<QP_XOR2>(p2); p3 += qdpp<QP_XOR2>(p3);

        // own-gate activation (gate q): 0=i,1=f sig; 2=g tanh; 3=o sig
        const float own = (q == 0) ? p0 : (q == 1) ? p1 : (q == 2) ? p2 : p3;
        const float pre = own + pcq;
        const bool  isg = (q == 2);
        const float e   = __expf(isg ? 2.0f * pre : -pre);
        const float t   = __builtin_amdgcn_rcpf(1.0f + e);
        const float a   = isg ? 1.0f - 2.0f * t : t;

        // broadcast activated gates across the quad
        const float ai = qdpp<QP_BC0>(a);
        const float af = qdpp<QP_BC1>(a);
        const float ag = qdpp<QP_BC2>(a);
        const float ao = qdpp<QP_BC3>(a);

        c = af * c + ai * ag;
        const float ec = __expf(2.0f * c);
        const float tc = __builtin_amdgcn_rcpf(1.0f + ec);
        hn = ao * (1.0f - 2.0f * tc);      // h_new = o * tanh(c)

        if (q == 0) {
            hh2[nxt][cell] = (_Float16)hn;                 // recurrence (f16)
            hist[(size_t)r * HH + cell] = hn;              // heads input (f32)
        }

        pcq = pn1; pn1 = pn2;

        // raw barrier: drain LDS only — P loads stay in flight across it
        asm volatile("s_waitcnt lgkmcnt(0)" ::: "memory");
        __builtin_amdgcn_s_barrier();
        __builtin_amdgcn_sched_barrier(0);
    }

    if (q == 0) {
        state[cell]      = hn;
        state[HH + cell] = c;
    }
}

// ---------------------------------------------------------------------------
// Kernel 3: heads, trivially parallel over (t, output). 16 threads per t
// (one idle), full 128-dot each in f32.
// ---------------------------------------------------------------------------
__global__ __launch_bounds__(256, 4) void heads_kernel(
    const float* __restrict__ hist,
    const float* __restrict__ W1, const float* __restrict__ b1,
    const float* __restrict__ W2, const float* __restrict__ b2,
    const float* __restrict__ W3, const float* __restrict__ b3,
    const float* __restrict__ W4, const float* __restrict__ b4,
    float* __restrict__ out, int t0, int C)
{
    const int idx = blockIdx.x * 256 + threadIdx.x;
    const int tr  = idx >> 4;
    const int oi  = idx & 15;
    if (tr >= C || oi >= 15) return;

    const float* wrow;
    float bias;
    if (oi < 11)       { wrow = W1 + oi * HH;        bias = b1[oi]; }
    else if (oi < 13)  { wrow = W2 + (oi - 11) * HH; bias = b2[oi - 11]; }
    else if (oi == 13) { wrow = W3;                  bias = b3[0]; }
    else               { wrow = W4;                  bias = b4[0]; }

    const float4* h4 = reinterpret_cast<const float4*>(hist + (size_t)tr * HH);
    const float4* w4 = reinterpret_cast<const float4*>(wrow);
    float s = bias;
#pragma unroll
    for (int k = 0; k < HH / 4; ++k) {
        float4 hv = h4[k];
        float4 wv = w4[k];
        s += hv.x*wv.x + hv.y*wv.y + hv.z*wv.z + hv.w*wv.w;
    }
    const int t = t0 + tr;
    if (oi < 11)       out[(size_t)t * 11 + oi] = s;
    else if (oi < 13)  out[OFF_EXP + (size_t)t * 2 + (oi - 11)] = s;
    else if (oi == 13) out[OFF_RSD + t] = s;
    else               out[OFF_S + t] = s;
}

// ---------------------------------------------------------------------------
extern "C" void kernel_launch(void* const* d_in, const int* in_sizes, int n_in,
                              void* d_out, int out_size, void* d_ws, size_t ws_size,
                              hipStream_t stream)
{
    const float* X    = (const float*)d_in[0];
    const float* W_ih = (const float*)d_in[1];
    const float* W_hh = (const float*)d_in[2];
    const float* b_ih = (const float*)d_in[3];
    const float* b_hh = (const float*)d_in[4];
    const float* W1   = (const float*)d_in[5];
    const float* b1   = (const float*)d_in[6];
    const float* W2   = (const float*)d_in[7];
    const float* b2   = (const float*)d_in[8];
    const float* W3   = (const float*)d_in[9];
    const float* b3   = (const float*)d_in[10];
    const float* W4   = (const float*)d_in[11];
    const float* b4   = (const float*)d_in[12];

    float* out   = (float*)d_out;
    float* state = (float*)d_ws;   // 256 floats: h then c

    // ws layout: state(1KB) | hist(C*128 f32) | P(C*512 f32)  => 2560 B/row
    size_t avail = (ws_size > 1024) ? (ws_size - 1024) / 2560 : 0;
    int C = (avail >= (size_t)T_STEPS) ? T_STEPS : (int)avail;
    if (C < 1) C = 1;
    float* hist = state + 256;
    float* P    = hist + (size_t)C * HH;

    for (int t0 = 0; t0 < T_STEPS; t0 += C) {
        const int Cc = (C < T_STEPS - t0) ? C : (T_STEPS - t0);
        const int nb = (Cc < 512) ? Cc : 512;
        pregate_kernel<<<nb, 512, 0, stream>>>(X, W_ih, b_ih, b_hh, P, t0, Cc);
        lstm_seq_kernel<<<1, 512, 0, stream>>>(P, W_hh, hist, state, t0, Cc);
        heads_kernel<<<(Cc * 16 + 255) / 256, 256, 0, stream>>>(
            hist, W1, b1, W2, b2, W3, b3, W4, b4, out, t0, Cc);
    }
}

// Round 4
// 17142.404 us; speedup vs baseline: 5.8473x; 1.0047x over previous
//
#include <hip/hip_runtime.h>
#include <hip/hip_bf16.h>
#include <cstdint>
#include <cstddef>

#define T_STEPS 32768
#define DD 64
#define HH 128
#define GG 512   // 4*H

// d_out layout (float32, concatenated flat):
//   step (T,11) @0, experience (T,2) @360448, rsd (T,1) @425984, s (T,1) @458752
#define OFF_EXP 360448
#define OFF_RSD 425984
#define OFF_S   458752

typedef __attribute__((ext_vector_type(2))) _Float16 half2v;

__device__ __forceinline__ int   f2i(float x) { union { float f; int i; } u; u.f = x; return u.i; }
__device__ __forceinline__ float i2f(int x)   { union { int i; float f; } u; u.i = x; return u.f; }

template<int CTRL>
__device__ __forceinline__ float qdpp(float v) {
    return i2f(__builtin_amdgcn_mov_dpp(f2i(v), CTRL, 0xf, 0xf, true));
}
#define QP_XOR1 0xB1  // (1,0,3,2)
#define QP_XOR2 0x4E  // (2,3,0,1)
#define QP_BC0  0x00
#define QP_BC1  0x55
#define QP_BC2  0xAA
#define QP_BC3  0xFF

__device__ __forceinline__ float dot2(unsigned w, unsigned h, float acc) {
    union { unsigned u; half2v h; } a, b;
    a.u = w; b.u = h;
    return __builtin_amdgcn_fdot2(a.h, b.h, acc, false);
}
__device__ __forceinline__ unsigned packh2(float x, float y) {
    union { half2v h; unsigned u; } c;
    c.h[0] = (_Float16)x; c.h[1] = (_Float16)y;
    return c.u;
}
__device__ __forceinline__ float exp2_f(float x) {
    float r; asm("v_exp_f32 %0, %1" : "=v"(r) : "v"(x)); return r;
}

// ---------------------------------------------------------------------------
// Kernel 1: pregate, PERMUTED: P[r][j] = pregate of gate (j&3) of cell (j>>2)
// ---------------------------------------------------------------------------
__global__ __launch_bounds__(512, 2) void pregate_kernel(
    const float* __restrict__ X, const float* __restrict__ W_ih,
    const float* __restrict__ b_ih, const float* __restrict__ b_hh,
    float* __restrict__ P, int t0, int nrows)
{
    __shared__ __align__(16) float xs[DD];
    const int j = threadIdx.x;
    const int grow = (j & 3) * HH + (j >> 2);

    float w[DD];
    const float4* wv = reinterpret_cast<const float4*>(W_ih + (size_t)grow * DD);
#pragma unroll
    for (int k = 0; k < DD / 4; ++k) {
        float4 v = wv[k];
        w[4*k+0] = v.x; w[4*k+1] = v.y; w[4*k+2] = v.z; w[4*k+3] = v.w;
    }
    const float bias = b_ih[grow] + b_hh[grow];

    const int rpb = (nrows + gridDim.x - 1) / gridDim.x;
    const int r0  = blockIdx.x * rpb;
    const int r1  = (r0 + rpb < nrows) ? (r0 + rpb) : nrows;

    for (int r = r0; r < r1; ++r) {
        const int t = t0 + r;
        if (j < DD) xs[j] = X[(size_t)t * DD + j];
        __syncthreads();
        float acc = bias;
        const float4* xv = reinterpret_cast<const float4*>(xs);
#pragma unroll
        for (int k = 0; k < DD / 4; ++k) {
            float4 v = xv[k];
            acc += v.x*w[4*k+0] + v.y*w[4*k+1] + v.z*w[4*k+2] + v.w*w[4*k+3];
        }
        P[(size_t)r * GG + j] = acc;
        __syncthreads();
    }
}

// ---------------------------------------------------------------------------
// Kernel 2: sequential LSTM, 1 block x 512 threads, one raw barrier per step.
// Quad owns cell (j>>2); lane q holds quarter-q of all 4 gate rows (64 packed
// f16x2). Per step: 4 broadcast ds_read_b128, 64 v_dot2, 12-op reduce-scatter
// (lane q ends with gate q), branch-free activation, 4 DPP broadcasts,
// replicated c update. h published via double-buffered f16 LDS.
// ---------------------------------------------------------------------------
__global__ __launch_bounds__(512, 2) void lstm_seq_kernel(
    const float* __restrict__ P, const float* __restrict__ W_hh,
    float* __restrict__ hist, float* __restrict__ state,
    int t0, int C)
{
    __shared__ __align__(16) _Float16 hh2[2][HH];

    const int j    = threadIdx.x;
    const int cell = j >> 2;
    const int q    = j & 3;

    // W_hh quarters -> 64 packed f16x2 registers
    unsigned w2[64];
#pragma unroll
    for (int g = 0; g < 4; ++g) {
        const float* wr = W_hh + (size_t)(g * HH + cell) * HH + 32 * q;
#pragma unroll
        for (int k = 0; k < 16; ++k)
            w2[g * 16 + k] = packh2(wr[2*k], wr[2*k+1]);
    }
#pragma unroll
    for (int i = 0; i < 64; ++i) asm volatile("" : "+v"(w2[i]));

    // branch-free activation constants (per-lane, hoisted):
    //   act(x) = fma(rcp(1 + exp2(x*sA)), sB, sC)
    //   q!=2 (sigmoid): sA=-log2(e), sB=1,  sC=0
    //   q==2 (tanh):    sA=2*log2(e), sB=-2, sC=1
    const bool  isg = (q == 2);
    const float sA  = isg ?  2.885390082f : -1.442695041f;
    const float sB  = isg ? -2.0f : 1.0f;
    const float sC  = isg ?  1.0f : 0.0f;

    float c = 0.0f;
    if (t0 != 0) c = state[HH + cell];
    if (j < HH) hh2[0][j] = (_Float16)((t0 != 0) ? state[j] : 0.0f);
    __syncthreads();

    const _Float16* hb0 = &hh2[0][32 * q];
    const _Float16* hb1 = &hh2[1][32 * q];

    float pcq = P[j];
    float pn1 = (C > 1) ? P[GG + j] : 0.0f;
    float hn  = 0.0f;

#pragma unroll 1
    for (int r = 0; r < C; ++r) {
        // h quarter: 4 broadcast b128 reads (first thing after barrier)
        const uint4* hp = reinterpret_cast<const uint4*>((r & 1) ? hb1 : hb0);
        const uint4 h0 = hp[0], h1 = hp[1], h2 = hp[2], h3 = hp[3];

        // prefetch P two steps ahead
        float pn2 = 0.0f;
        if (r + 2 < C) pn2 = P[(size_t)(r + 2) * GG + j];

        float p0 = 0.f, p1 = 0.f, p2 = 0.f, p3 = 0.f;
#define DOTK(hx, k) \
        p0 = dot2(w2[k],      hx, p0); p1 = dot2(w2[16 + k], hx, p1); \
        p2 = dot2(w2[32 + k], hx, p2); p3 = dot2(w2[48 + k], hx, p3);
        DOTK(h0.x, 0)  DOTK(h0.y, 1)  DOTK(h0.z, 2)  DOTK(h0.w, 3)
        DOTK(h1.x, 4)  DOTK(h1.y, 5)  DOTK(h1.z, 6)  DOTK(h1.w, 7)
        DOTK(h2.x, 8)  DOTK(h2.y, 9)  DOTK(h2.z, 10) DOTK(h2.w, 11)
        DOTK(h3.x, 12) DOTK(h3.y, 13) DOTK(h3.z, 14) DOTK(h3.w, 15)
#undef DOTK

        // reduce-scatter: stage XOR2 (keep 2, send 2), stage XOR1 (keep 1)
        float ka = (q & 2) ? p2 : p0;
        float kb = (q & 2) ? p3 : p1;
        float sa = (q & 2) ? p0 : p2;
        float sb = (q & 2) ? p1 : p3;
        ka += qdpp<QP_XOR2>(sa);
        kb += qdpp<QP_XOR2>(sb);
        float own = (q & 1) ? kb : ka;
        float snd = (q & 1) ? ka : kb;
        own += qdpp<QP_XOR1>(snd);

        // activation (lane q activates gate q), branch-free
        const float pre = own + pcq;
        const float t   = __builtin_amdgcn_rcpf(1.0f + exp2_f(pre * sA));
        const float a   = __builtin_fmaf(t, sB, sC);

        // broadcast activated gates across the quad
        const float ai = qdpp<QP_BC0>(a);
        const float af = qdpp<QP_BC1>(a);
        const float ag = qdpp<QP_BC2>(a);
        const float ao = qdpp<QP_BC3>(a);

        c = __builtin_fmaf(af, c, ai * ag);
        const float tc = __builtin_amdgcn_rcpf(1.0f + exp2_f(c * 2.885390082f));
        hn = ao * __builtin_fmaf(tc, -2.0f, 1.0f);   // o * tanh(c)

        if (q == 0) {
            hh2[(r & 1) ^ 1][cell] = (_Float16)hn;
            hist[(size_t)r * HH + cell] = hn;
        }

        pcq = pn1; pn1 = pn2;

        asm volatile("s_waitcnt lgkmcnt(0)" ::: "memory");
        __builtin_amdgcn_s_barrier();
        __builtin_amdgcn_sched_barrier(0);
    }

    if (q == 0) {
        state[cell]      = hn;
        state[HH + cell] = c;
    }
}

// ---------------------------------------------------------------------------
// Kernel 3: heads, parallel over (t, output)
// ---------------------------------------------------------------------------
__global__ __launch_bounds__(256, 4) void heads_kernel(
    const float* __restrict__ hist,
    const float* __restrict__ W1, const float* __restrict__ b1,
    const float* __restrict__ W2, const float* __restrict__ b2,
    const float* __restrict__ W3, const float* __restrict__ b3,
    const float* __restrict__ W4, const float* __restrict__ b4,
    float* __restrict__ out, int t0, int C)
{
    const int idx = blockIdx.x * 256 + threadIdx.x;
    const int tr  = idx >> 4;
    const int oi  = idx & 15;
    if (tr >= C || oi >= 15) return;

    const float* wrow;
    float bias;
    if (oi < 11)       { wrow = W1 + oi * HH;        bias = b1[oi]; }
    else if (oi < 13)  { wrow = W2 + (oi - 11) * HH; bias = b2[oi - 11]; }
    else if (oi == 13) { wrow = W3;                  bias = b3[0]; }
    else               { wrow = W4;                  bias = b4[0]; }

    const float4* h4 = reinterpret_cast<const float4*>(hist + (size_t)tr * HH);
    const float4* w4 = reinterpret_cast<const float4*>(wrow);
    float s = bias;
#pragma unroll
    for (int k = 0; k < HH / 4; ++k) {
        float4 hv = h4[k];
        float4 wv = w4[k];
        s += hv.x*wv.x + hv.y*wv.y + hv.z*wv.z + hv.w*wv.w;
    }
    const int t = t0 + tr;
    if (oi < 11)       out[(size_t)t * 11 + oi] = s;
    else if (oi < 13)  out[OFF_EXP + (size_t)t * 2 + (oi - 11)] = s;
    else if (oi == 13) out[OFF_RSD + t] = s;
    else               out[OFF_S + t] = s;
}

// ---------------------------------------------------------------------------
extern "C" void kernel_launch(void* const* d_in, const int* in_sizes, int n_in,
                              void* d_out, int out_size, void* d_ws, size_t ws_size,
                              hipStream_t stream)
{
    const float* X    = (const float*)d_in[0];
    const float* W_ih = (const float*)d_in[1];
    const float* W_hh = (const float*)d_in[2];
    const float* b_ih = (const float*)d_in[3];
    const float* b_hh = (const float*)d_in[4];
    const float* W1   = (const float*)d_in[5];
    const float* b1   = (const float*)d_in[6];
    const float* W2   = (const float*)d_in[7];
    const float* b2   = (const float*)d_in[8];
    const float* W3   = (const float*)d_in[9];
    const float* b3   = (const float*)d_in[10];
    const float* W4   = (const float*)d_in[11];
    const float* b4   = (const float*)d_in[12];

    float* out   = (float*)d_out;
    float* state = (float*)d_ws;   // 256 floats: h then c

    // ws: state(1KB) | hist(C*128 f32) | P(C*512 f32)  => 2560 B/row
    size_t avail = (ws_size > 1024) ? (ws_size - 1024) / 2560 : 0;
    int C = (avail >= (size_t)T_STEPS) ? T_STEPS : (int)avail;
    if (C < 1) C = 1;
    float* hist = state + 256;
    float* P    = hist + (size_t)C * HH;

    for (int t0 = 0; t0 < T_STEPS; t0 += C) {
        const int Cc = (C < T_STEPS - t0) ? C : (T_STEPS - t0);
        const int nb = (Cc < 512) ? Cc : 512;
        pregate_kernel<<<nb, 512, 0, stream>>>(X, W_ih, b_ih, b_hh, P, t0, Cc);
        lstm_seq_kernel<<<1, 512, 0, stream>>>(P, W_hh, hist, state, t0, Cc);
        heads_kernel<<<(Cc * 16 + 255) / 256, 256, 0, stream>>>(
            hist, W1, b1, W2, b2, W3, b3, W4, b4, out, t0, Cc);
    }
}

// Round 5
// 16587.079 us; speedup vs baseline: 6.0431x; 1.0335x over previous
//
#include <hip/hip_runtime.h>
#include <hip/hip_bf16.h>
#include <cstdint>
#include <cstddef>

#define T_STEPS 32768
#define DD 64
#define HH 128
#define GG 512   // 4*H

// d_out layout (float32, concatenated flat):
//   step (T,11) @0, experience (T,2) @360448, rsd (T,1) @425984, s (T,1) @458752
#define OFF_EXP 360448
#define OFF_RSD 425984
#define OFF_S   458752

typedef __attribute__((ext_vector_type(8))) _Float16 half8;
typedef __attribute__((ext_vector_type(4))) float f32x4;

__device__ __forceinline__ float exp2_f(float x) {
    float r; asm("v_exp_f32 %0, %1" : "=v"(r) : "v"(x)); return r;
}

// Owned-gate permutation shared by pregate and the seq kernel:
// thread j (=64w+l) owns W_hh row grow(j) =
//   (j&3)*128 + (j>>6)*16 + ((j>>4)&3)*4 + ((j&15)>>2)
__device__ __forceinline__ int grow_of(int j) {
    return (j & 3) * HH + (j >> 6) * 16 + ((j >> 4) & 3) * 4 + ((j & 15) >> 2);
}

// ---------------------------------------------------------------------------
// Kernel 1: pregate, permuted: P[r][j] = pregate of row grow_of(j)
// ---------------------------------------------------------------------------
__global__ __launch_bounds__(512, 2) void pregate_kernel(
    const float* __restrict__ X, const float* __restrict__ W_ih,
    const float* __restrict__ b_ih, const float* __restrict__ b_hh,
    float* __restrict__ P, int t0, int nrows)
{
    __shared__ __align__(16) float xs[DD];
    const int j = threadIdx.x;
    const int grow = grow_of(j);

    float w[DD];
    const float4* wv = reinterpret_cast<const float4*>(W_ih + (size_t)grow * DD);
#pragma unroll
    for (int k = 0; k < DD / 4; ++k) {
        float4 v = wv[k];
        w[4*k+0] = v.x; w[4*k+1] = v.y; w[4*k+2] = v.z; w[4*k+3] = v.w;
    }
    const float bias = b_ih[grow] + b_hh[grow];

    const int rpb = (nrows + gridDim.x - 1) / gridDim.x;
    const int r0  = blockIdx.x * rpb;
    const int r1  = (r0 + rpb < nrows) ? (r0 + rpb) : nrows;

    for (int r = r0; r < r1; ++r) {
        const int t = t0 + r;
        if (j < DD) xs[j] = X[(size_t)t * DD + j];
        __syncthreads();
        float acc = bias;
        const float4* xv = reinterpret_cast<const float4*>(xs);
#pragma unroll
        for (int k = 0; k < DD / 4; ++k) {
            float4 v = xv[k];
            acc += v.x*w[4*k+0] + v.y*w[4*k+1] + v.z*w[4*k+2] + v.w*w[4*k+3];
        }
        P[(size_t)r * GG + j] = acc;
        __syncthreads();
    }
}

// ---------------------------------------------------------------------------
// Kernel 2: sequential LSTM, 1 block x 512 threads (8 waves), MFMA matvec.
//   A (mfma op0) = h replicated over 16 rows: lane reads 8 f16 at
//                  hh[32*kt + 8*kgrp] (broadcast ds_read_b128).
//   B (mfma op1) = W_hh columns: tile mt col (l&15) is W row
//                  lr = 16*mt + (l&15); gt = lr&3 = l&3, cell = 16w + (lr>>2).
//   D: cols = gates, rows replicated -> lane's acc[mt][0] = gate sum for
//      lr = 16*mt + (l&15). Lane owns lr = 16*kgrp + (l&15) (3-cndmask sel).
// Per step: 4 ds_read_b128 (h) + 16 MFMA + 1 act/lane + in-wave LDS
// redistribute + cell update on lanes 0..15 + ONE raw barrier.
// ---------------------------------------------------------------------------
__global__ __launch_bounds__(512, 2) void lstm_seq_kernel(
    const float* __restrict__ P, const float* __restrict__ W_hh,
    float* __restrict__ hist, float* __restrict__ state,
    int t0, int C)
{
    __shared__ __align__(16) _Float16 hh2[2][HH];
    __shared__ __align__(16) float gate_lds[GG];

    const int j    = threadIdx.x;
    const int w    = j >> 6;
    const int l    = j & 63;
    const int col  = l & 15;
    const int kgrp = l >> 4;     // 0..3
    const int gt   = l & 3;      // owned gate type: 0=i 1=f 2=g(tanh) 3=o

    // ---- B fragments: W_hh columns -> 64 packed f16 registers (AGPR-ok)
    half8 wf[4][4];
#pragma unroll
    for (int mt = 0; mt < 4; ++mt) {
        const int growB = gt * HH + 16 * w + 4 * mt + (col >> 2);
        const float* wr = W_hh + (size_t)growB * HH + 8 * kgrp;
#pragma unroll
        for (int kt = 0; kt < 4; ++kt) {
            const float* wp = wr + 32 * kt;
            float4 w0 = *reinterpret_cast<const float4*>(wp);
            float4 w1 = *reinterpret_cast<const float4*>(wp + 4);
            half8 hf;
            hf[0] = (_Float16)w0.x; hf[1] = (_Float16)w0.y;
            hf[2] = (_Float16)w0.z; hf[3] = (_Float16)w0.w;
            hf[4] = (_Float16)w1.x; hf[5] = (_Float16)w1.y;
            hf[6] = (_Float16)w1.z; hf[7] = (_Float16)w1.w;
            wf[mt][kt] = hf;
        }
    }

    // branch-free activation constants (R3/R4-verified formula)
    const bool  isg = (gt == 2);
    const float sA  = isg ?  2.885390082f : -1.442695041f;
    const float sB  = isg ? -2.0f : 1.0f;
    const float sC  = isg ?  1.0f : 0.0f;
    const bool  b0  = (kgrp & 1) != 0;
    const bool  b1  = (kgrp & 2) != 0;

    const int mycell = 16 * w + l;        // cell owned by lanes l<16
    float c = 0.0f;
    if (t0 != 0 && l < 16) c = state[HH + mycell];
    if (j < HH) hh2[0][j] = (_Float16)((t0 != 0) ? state[j] : 0.0f);
    __syncthreads();

    float pcq = P[j];
    float pn1 = (C > 1) ? P[GG + j] : 0.0f;
    const float* pp = P + 2 * (size_t)GG + j;
    float* hw = hist + mycell;
    float hn = 0.0f;
    const f32x4 Z = {0.0f, 0.0f, 0.0f, 0.0f};

#pragma unroll 1
    for (int r = 0; r < C; ++r) {
        // A fragments: h broadcast reads (4 x ds_read_b128)
        const _Float16* hb = &hh2[r & 1][8 * kgrp];
        const half8 a0 = *reinterpret_cast<const half8*>(hb);
        const half8 a1 = *reinterpret_cast<const half8*>(hb + 32);
        const half8 a2 = *reinterpret_cast<const half8*>(hb + 64);
        const half8 a3 = *reinterpret_cast<const half8*>(hb + 96);

        // P prefetch 2 steps ahead (stays in flight across the raw barrier)
        float pn2 = 0.0f;
        if (r + 2 < C) pn2 = *pp;
        pp += GG;

        // 16 MFMA: 4 independent kt-chains, C-in = constant zero vec
        f32x4 q0 = __builtin_amdgcn_mfma_f32_16x16x32_f16(a0, wf[0][0], Z, 0, 0, 0);
        f32x4 q1 = __builtin_amdgcn_mfma_f32_16x16x32_f16(a0, wf[1][0], Z, 0, 0, 0);
        f32x4 q2 = __builtin_amdgcn_mfma_f32_16x16x32_f16(a0, wf[2][0], Z, 0, 0, 0);
        f32x4 q3 = __builtin_amdgcn_mfma_f32_16x16x32_f16(a0, wf[3][0], Z, 0, 0, 0);
        q0 = __builtin_amdgcn_mfma_f32_16x16x32_f16(a1, wf[0][1], q0, 0, 0, 0);
        q1 = __builtin_amdgcn_mfma_f32_16x16x32_f16(a1, wf[1][1], q1, 0, 0, 0);
        q2 = __builtin_amdgcn_mfma_f32_16x16x32_f16(a1, wf[2][1], q2, 0, 0, 0);
        q3 = __builtin_amdgcn_mfma_f32_16x16x32_f16(a1, wf[3][1], q3, 0, 0, 0);
        q0 = __builtin_amdgcn_mfma_f32_16x16x32_f16(a2, wf[0][2], q0, 0, 0, 0);
        q1 = __builtin_amdgcn_mfma_f32_16x16x32_f16(a2, wf[1][2], q1, 0, 0, 0);
        q2 = __builtin_amdgcn_mfma_f32_16x16x32_f16(a2, wf[2][2], q2, 0, 0, 0);
        q3 = __builtin_amdgcn_mfma_f32_16x16x32_f16(a2, wf[3][2], q3, 0, 0, 0);
        q0 = __builtin_amdgcn_mfma_f32_16x16x32_f16(a3, wf[0][3], q0, 0, 0, 0);
        q1 = __builtin_amdgcn_mfma_f32_16x16x32_f16(a3, wf[1][3], q1, 0, 0, 0);
        q2 = __builtin_amdgcn_mfma_f32_16x16x32_f16(a3, wf[2][3], q2, 0, 0, 0);
        q3 = __builtin_amdgcn_mfma_f32_16x16x32_f16(a3, wf[3][3], q3, 0, 0, 0);

        // select owned gate sum: mt = kgrp (rows replicated -> reg 0)
        const float s01  = b0 ? q1[0] : q0[0];
        const float s23  = b0 ? q3[0] : q2[0];
        const float ssum = b1 ? s23 : s01;

        // activation (1 exp + 1 rcp per lane, branch-free)
        const float pre = ssum + pcq;
        const float t   = __builtin_amdgcn_rcpf(1.0f + exp2_f(pre * sA));
        const float a   = __builtin_fmaf(t, sB, sC);

        // in-wave redistribute: lr_own = 16*kgrp + col, region 64w..64w+64
        gate_lds[64 * w + 16 * kgrp + col] = a;
        asm volatile("s_waitcnt lgkmcnt(0)" ::: "memory");

        if (l < 16) {
            // gates (i,f,g,o) of cell 16w+l are 4 consecutive floats
            const f32x4 g4 = *reinterpret_cast<const f32x4*>(&gate_lds[64 * w + 4 * l]);
            c = __builtin_fmaf(g4[1], c, g4[0] * g4[2]);
            const float tc = __builtin_amdgcn_rcpf(1.0f + exp2_f(c * 2.885390082f));
            hn = g4[3] * __builtin_fmaf(tc, -2.0f, 1.0f);   // o * tanh(c)
            hh2[(r & 1) ^ 1][mycell] = (_Float16)hn;
            *hw = hn;                                        // heads input
        }
        hw += HH;
        pcq = pn1; pn1 = pn2;

        // single raw barrier: drain LDS only, P loads stay in flight
        asm volatile("s_waitcnt lgkmcnt(0)" ::: "memory");
        __builtin_amdgcn_s_barrier();
        __builtin_amdgcn_sched_barrier(0);
    }

    if (l < 16) {
        state[mycell]      = hn;
        state[HH + mycell] = c;
    }
}

// ---------------------------------------------------------------------------
// Kernel 3: heads, parallel over (t, output)
// ---------------------------------------------------------------------------
__global__ __launch_bounds__(256, 4) void heads_kernel(
    const float* __restrict__ hist,
    const float* __restrict__ W1, const float* __restrict__ b1,
    const float* __restrict__ W2, const float* __restrict__ b2,
    const float* __restrict__ W3, const float* __restrict__ b3,
    const float* __restrict__ W4, const float* __restrict__ b4,
    float* __restrict__ out, int t0, int C)
{
    const int idx = blockIdx.x * 256 + threadIdx.x;
    const int tr  = idx >> 4;
    const int oi  = idx & 15;
    if (tr >= C || oi >= 15) return;

    const float* wrow;
    float bias;
    if (oi < 11)       { wrow = W1 + oi * HH;        bias = b1[oi]; }
    else if (oi < 13)  { wrow = W2 + (oi - 11) * HH; bias = b2[oi - 11]; }
    else if (oi == 13) { wrow = W3;                  bias = b3[0]; }
    else               { wrow = W4;                  bias = b4[0]; }

    const float4* h4 = reinterpret_cast<const float4*>(hist + (size_t)tr * HH);
    const float4* w4 = reinterpret_cast<const float4*>(wrow);
    float s = bias;
#pragma unroll
    for (int k = 0; k < HH / 4; ++k) {
        float4 hv = h4[k];
        float4 wv = w4[k];
        s += hv.x*wv.x + hv.y*wv.y + hv.z*wv.z + hv.w*wv.w;
    }
    const int t = t0 + tr;
    if (oi < 11)       out[(size_t)t * 11 + oi] = s;
    else if (oi < 13)  out[OFF_EXP + (size_t)t * 2 + (oi - 11)] = s;
    else if (oi == 13) out[OFF_RSD + t] = s;
    else               out[OFF_S + t] = s;
}

// ---------------------------------------------------------------------------
extern "C" void kernel_launch(void* const* d_in, const int* in_sizes, int n_in,
                              void* d_out, int out_size, void* d_ws, size_t ws_size,
                              hipStream_t stream)
{
    const float* X    = (const float*)d_in[0];
    const float* W_ih = (const float*)d_in[1];
    const float* W_hh = (const float*)d_in[2];
    const float* b_ih = (const float*)d_in[3];
    const float* b_hh = (const float*)d_in[4];
    const float* W1   = (const float*)d_in[5];
    const float* b1   = (const float*)d_in[6];
    const float* W2   = (const float*)d_in[7];
    const float* b2   = (const float*)d_in[8];
    const float* W3   = (const float*)d_in[9];
    const float* b3   = (const float*)d_in[10];
    const float* W4   = (const float*)d_in[11];
    const float* b4   = (const float*)d_in[12];

    float* out   = (float*)d_out;
    float* state = (float*)d_ws;   // 256 floats: h then c

    // ws: state(1KB) | hist(C*128 f32) | P(C*512 f32)  => 2560 B/row
    size_t avail = (ws_size > 1024) ? (ws_size - 1024) / 2560 : 0;
    int C = (avail >= (size_t)T_STEPS) ? T_STEPS : (int)avail;
    if (C < 1) C = 1;
    float* hist = state + 256;
    float* P    = hist + (size_t)C * HH;

    for (int t0 = 0; t0 < T_STEPS; t0 += C) {
        const int Cc = (C < T_STEPS - t0) ? C : (T_STEPS - t0);
        const int nb = (Cc < 512) ? Cc : 512;
        pregate_kernel<<<nb, 512, 0, stream>>>(X, W_ih, b_ih, b_hh, P, t0, Cc);
        lstm_seq_kernel<<<1, 512, 0, stream>>>(P, W_hh, hist, state, t0, Cc);
        heads_kernel<<<(Cc * 16 + 255) / 256, 256, 0, stream>>>(
            hist, W1, b1, W2, b2, W3, b3, W4, b4, out, t0, Cc);
    }
}